// Round 13
// baseline (117.992 us; speedup 1.0000x reference)
//
#include <hip/hip_runtime.h>
#include <hip/hip_bf16.h>
#include <stdint.h>

typedef float  f32x4  __attribute__((ext_vector_type(4)));
typedef short  bf16x8 __attribute__((ext_vector_type(8)));
typedef short  bf16x4 __attribute__((ext_vector_type(4)));

#define C_IN   384
#define C_OUT  384
#define Hdim   56
#define Wdim   56
#define HWsz   3136
#define KC     32
#define NCHUNK 12
#define NOSUB  24
#define SLAB   ((size_t)HWsz * 8)    // shorts per (n,cblk,g) slab
#define BSTR   ((size_t)HWsz * KC)   // shorts per (n,cblk) = 4 slabs
#define RB     7                     // output rows per wave (dw); halo 9/7 = 1.29x
#define NRB    (Hdim / RB)           // 8
#define NBLKDW (NRB * NCHUNK * 32)   // 3072, %8==0
#define NPREP  ((C_OUT * C_IN) / 256) // 576 prep blocks folded into dw grid

__device__ __forceinline__ short f2bf(float f) {
    union { float f; uint32_t u; } v; v.f = f;
    uint32_t u = v.u + (0x7FFFu + ((v.u >> 16) & 1u));   // RNE
    return (short)(u >> 16);
}

__device__ __forceinline__ uint32_t cvtpk_bf16(float lo, float hi) {
    uint32_t r;
    asm("v_cvt_pk_bf16_f32 %0, %1, %2" : "=v"(r) : "v"(lo), "v"(hi));
    return r;   // lo in bits[15:0], hi in bits[31:16]
}

__device__ __forceinline__ void stage16(const short* g, const short* l) {
    __builtin_amdgcn_global_load_lds(
        (const __attribute__((address_space(1))) void*)g,
        (__attribute__((address_space(3))) void*)l, 16, 0, 0);
}

template<int N> __device__ __forceinline__ void wait_vmcnt() {
    if constexpr (N == 0)      asm volatile("s_waitcnt vmcnt(0)" ::: "memory");
    else if constexpr (N == 1) asm volatile("s_waitcnt vmcnt(1)" ::: "memory");
    else                       asm volatile("s_waitcnt vmcnt(2)" ::: "memory");
}
__device__ __forceinline__ void block_barrier() {
    asm volatile("" ::: "memory");
    __builtin_amdgcn_s_barrier();
    asm volatile("" ::: "memory");
}

// ---------------- W prepack ----------------
// flat idx = ((cblk*24 + osub)*64 + lane)*8 + j
// value    = bf16( w_pw[ (osub*16 + (lane&15)) * 384 + cblk*32 + (lane>>4)*8 + j ] )
__device__ __forceinline__ void prep_w_one(const float* __restrict__ wpw,
                                           short* __restrict__ apre, int idx) {
    int j    = idx & 7;
    int lane = (idx >> 3) & 63;
    int osub = (idx >> 9) % NOSUB;
    int cblk = idx / (NOSUB * 512);
    int o = osub * 16 + (lane & 15);
    int c = cblk * KC + (lane >> 4) * 8 + j;
    apre[idx] = f2bf(wpw[o * C_IN + c]);
}

__global__ void prep_w_kernel(const float* __restrict__ wpw, short* __restrict__ apre) {
    int idx = blockIdx.x * 256 + threadIdx.x;
    if (idx < C_OUT * C_IN) prep_w_one(wpw, apre, idx);
}

// ---------------- Depthwise v10 + folded W-prepack ----------------
// Wave = 8 ch x 7 output rows (9 input rows, halo 1.29x vs 1.5x at RB=4).
// 72 loads issued wide, pinned by vmcnt(0) fence; (256,4) caps VGPR at 128.
// Vertical-first conv + packed shuffles. Stores slab-contiguous 16B/lane.
__global__ __launch_bounds__(256, 4) void dw_kernel(
    const float* __restrict__ x, const float* __restrict__ wdw,
    const float* __restrict__ wpw, short* __restrict__ apre,
    short* __restrict__ dwws) {

    const int p = (int)blockIdx.x;
    if (p >= NBLKDW) {   // folded prepack
        const int idx = (p - NBLKDW) * 256 + (int)threadIdx.x;
        if (idx < C_OUT * C_IN) prep_w_one(wpw, apre, idx);
        return;
    }

    const int l  = (p & 7) * (NBLKDW / 8) + (p >> 3);
    const int rb   = l % NRB;
    const int cblk = (l / NRB) % NCHUNK;
    const int n    = l / (NRB * NCHUNK);

    const int wave = (int)threadIdx.x >> 6;
    const int lane = (int)threadIdx.x & 63;
    const int c0u  = __builtin_amdgcn_readfirstlane(cblk * KC + wave * 8);
    const int h0   = rb * RB;

    const float* xb = x + ((size_t)n * C_IN + c0u) * HWsz;

    // ---- issue ALL 72 loads (8 ch x 9 rows), pinned wide ----
    float v[8][RB + 2];
#pragma unroll
    for (int q = 0; q < 8; ++q)
#pragma unroll
        for (int d = 0; d < RB + 2; ++d) {
            const int hh = h0 + d - 1;
            const bool ok = (hh >= 0) && (hh < Hdim) && (lane < Wdim);
            v[q][d] = ok ? xb[(size_t)q * HWsz + hh * Wdim + lane] : 0.f;
        }
    asm volatile("s_waitcnt vmcnt(0)" ::: "memory");

    const float* wp = wdw + c0u * 9;
    float wk[8][9];
#pragma unroll
    for (int q = 0; q < 8; ++q)
#pragma unroll
        for (int t = 0; t < 9; ++t) wk[q][t] = wp[q * 9 + t];

    bf16x8 pk[RB];
#pragma unroll
    for (int qq = 0; qq < 8; qq += 2) {
#pragma unroll
        for (int r = 0; r < RB; ++r) {
            // vertical conv per channel pair: t_d = sum_dr w[dr*3+d]*v[r+dr]
            float tA[3], tB[3];
#pragma unroll
            for (int d = 0; d < 3; ++d) {
                tA[d] = wk[qq][d] * v[qq][r];
                tA[d] = fmaf(wk[qq][3 + d], v[qq][r + 1], tA[d]);
                tA[d] = fmaf(wk[qq][6 + d], v[qq][r + 2], tA[d]);
                tB[d] = wk[qq + 1][d] * v[qq + 1][r];
                tB[d] = fmaf(wk[qq + 1][3 + d], v[qq + 1][r + 1], tB[d]);
                tB[d] = fmaf(wk[qq + 1][6 + d], v[qq + 1][r + 2], tB[d]);
            }
            // horizontal combine: out(p) = t0(p-1) + t1(p) + t2(p+1)
            uint32_t p0 = cvtpk_bf16(tA[0], tB[0]);
            uint32_t p2 = cvtpk_bf16(tA[2], tB[2]);
            uint32_t l0 = __shfl_up(p0, 1);
            if (lane == 0) l0 = 0u;                  // left zero-pad
            uint32_t r2 = __shfl_down(p2, 1);        // lane55 pulls lane56 (zeros)
            const float lfA = __uint_as_float(l0 << 16);
            const float lfB = __uint_as_float(l0 & 0xFFFF0000u);
            const float rtA = __uint_as_float(r2 << 16);
            const float rtB = __uint_as_float(r2 & 0xFFFF0000u);
            pk[r][qq]     = f2bf(tA[1] + lfA + rtA);
            pk[r][qq + 1] = f2bf(tB[1] + lfB + rtB);
        }
    }

    if (lane < Wdim) {
        short* sb = dwws + (((size_t)n * NCHUNK + cblk) * 4 + wave) * SLAB;
#pragma unroll
        for (int r = 0; r < RB; ++r)
            *reinterpret_cast<bf16x8*>(sb + ((size_t)(h0 + r) * Wdim + lane) * 8)
                = pk[r];
    }
}

// ---------------- Pointwise GEMM v7: LDS-staged B, depth-3 pipeline, nt y-stores -----
// grid (49 pb, 32 n), 256 threads (4 waves). Wave owns 96 o x 64 pix.
// B layout [n][cblk][g][pix][c8], slab g = kb. Stage: thread t -> LDS unit t
// (linear); global source pixel XOR-swizzled (involution) for bank spread.
__global__ __launch_bounds__(256, 3) void pw_kernel(
    const short* __restrict__ apre, const short* __restrict__ dwws,
    float* __restrict__ y) {

    __shared__ __align__(16) short Bt[4][64 * KC];   // 4 x 4 KB

    const int pb   = blockIdx.x;
    const int n    = blockIdx.y;
    const int wave = (int)threadIdx.x >> 6;
    const int lane = (int)threadIdx.x & 63;
    const int col  = lane & 15;
    const int kb   = lane >> 4;

    f32x4 acc[6][4];
#pragma unroll
    for (int m = 0; m < 6; ++m)
#pragma unroll
        for (int q = 0; q < 4; ++q) acc[m][q] = (f32x4)0.f;

    // stage mapping: g = wave, physical pixel unit = lane
    const int plog = (lane & ~7) | ((lane ^ (lane >> 3) ^ (wave << 1)) & 7);
    const short* gsrc0 = dwws + (size_t)n * NCHUNK * BSTR + (size_t)wave * SLAB
                       + ((size_t)pb * 64 + plog) * 8;
    const short* lbase = &Bt[0][0] + (wave << 9);   // wave's 1KB quarter of buffer 0

    // read offsets: logical (kb, pix) lives at unit kb*64 + swz(kb, pix)
    int rd[4];
#pragma unroll
    for (int q = 0; q < 4; ++q) {
        const int pix = q * 16 + col;
        const int ppx = (pix & ~7) | ((pix ^ (pix >> 3) ^ (kb << 1)) & 7);
        rd[q] = (kb * 64 + ppx) * 8;
    }

#define STAGE(b, ch) stage16(gsrc0 + (size_t)(ch) * BSTR, lbase + (b) * (64 * KC))

    STAGE(0, 0);
    STAGE(1, 1);
    STAGE(2, 2);

#pragma unroll
    for (int ch = 0; ch < NCHUNK; ++ch) {
        if (ch <= NCHUNK - 3)      wait_vmcnt<2>();
        else if (ch == NCHUNK - 2) wait_vmcnt<1>();
        else                       wait_vmcnt<0>();
        block_barrier();

        // A-fragments first (their implicit wait never drains the stage below)
        bf16x8 af[6];
#pragma unroll
        for (int m = 0; m < 6; ++m)
            af[m] = *reinterpret_cast<const bf16x8*>(
                apre + (((ch * NOSUB + wave * 6 + m) * 64 + lane) << 3));

        if (ch + 3 < NCHUNK) STAGE((ch + 3) & 3, ch + 3);

        bf16x8 bfr[4];
#pragma unroll
        for (int q = 0; q < 4; ++q)
            bfr[q] = *reinterpret_cast<const bf16x8*>(&Bt[ch & 3][rd[q]]);

#pragma unroll
        for (int m = 0; m < 6; ++m)
#pragma unroll
            for (int q = 0; q < 4; ++q)
                acc[m][q] = __builtin_amdgcn_mfma_f32_16x16x32_bf16(
                    af[m], bfr[q], acc[m][q], 0, 0, 0);
    }
#undef STAGE

    // ---- epilogue: o = wave*96 + m*16 + kb*4 + r ; pix = q*16 + col ; nt stores ----
#pragma unroll
    for (int m = 0; m < 6; ++m) {
        const int o = wave * 96 + m * 16 + kb * 4;
        float* yo = y + ((size_t)(n * C_OUT + o)) * HWsz + pb * 64;
#pragma unroll
        for (int q = 0; q < 4; ++q) {
            const int pix = q * 16 + col;
#pragma unroll
            for (int r = 0; r < 4; ++r)
                __builtin_nontemporal_store(acc[m][q][r], yo + (size_t)r * HWsz + pix);
        }
    }
}

// ---------------- Fallback fused kernel (round-1, correct but slow) ----------------
#define LDSS 40
__global__ __launch_bounds__(512) void fused_dwpw_kernel(
    const float* __restrict__ x, const float* __restrict__ wdw,
    const short* __restrict__ apre, float* __restrict__ y) {

    __shared__ __align__(16) short dw_lds[64 * LDSS];

    const int h    = blockIdx.x;
    const int n    = blockIdx.y;
    const int tid  = (int)threadIdx.x;
    const int wave = tid >> 6;
    const int lane = tid & 63;
    const int col  = lane & 15;
    const int kb   = lane >> 4;

    f32x4 acc[3][4];
#pragma unroll
    for (int m = 0; m < 3; ++m)
#pragma unroll
        for (int p = 0; p < 4; ++p) acc[m][p] = (f32x4)0.f;

    const float* xn = x + (size_t)n * C_IN * HWsz;

    for (int ch = 0; ch < NCHUNK; ++ch) {
        short dwv[4];
#pragma unroll
        for (int q = 0; q < 4; ++q) {
            const int c = ch * KC + wave * 4 + q;
            const float* xc = xn + (size_t)c * HWsz;
            const float* wkp = wdw + c * 9;
            float a0 = 0.f;
#pragma unroll
            for (int r = 0; r < 3; ++r) {
                const int hh = h + r - 1;
                float xv = 0.f;
                if (hh >= 0 && hh < Hdim && lane < Wdim) xv = xc[hh * Wdim + lane];
                float lf = __shfl_up(xv, 1);
                if (lane == 0) lf = 0.f;
                float rt = __shfl_down(xv, 1);
                a0 = fmaf(wkp[r * 3 + 0], lf, a0);
                a0 = fmaf(wkp[r * 3 + 1], xv, a0);
                a0 = fmaf(wkp[r * 3 + 2], rt, a0);
            }
            if (lane >= Wdim) a0 = 0.f;
            dwv[q] = f2bf(a0);
        }

        __syncthreads();
        {
            bf16x4 pk2; pk2[0] = dwv[0]; pk2[1] = dwv[1]; pk2[2] = dwv[2]; pk2[3] = dwv[3];
            *reinterpret_cast<bf16x4*>(&dw_lds[lane * LDSS + wave * 4]) = pk2;
        }
        __syncthreads();

        bf16x8 afr[3], bfr[4];
#pragma unroll
        for (int m = 0; m < 3; ++m)
            afr[m] = *reinterpret_cast<const bf16x8*>(
                apre + (((ch * NOSUB + wave * 3 + m) * 64 + lane) << 3));
#pragma unroll
        for (int p = 0; p < 4; ++p)
            bfr[p] = *reinterpret_cast<const bf16x8*>(
                &dw_lds[(p * 16 + col) * LDSS + kb * 8]);
#pragma unroll
        for (int m = 0; m < 3; ++m)
#pragma unroll
            for (int p = 0; p < 4; ++p)
                acc[m][p] = __builtin_amdgcn_mfma_f32_16x16x32_bf16(
                    afr[m], bfr[p], acc[m][p], 0, 0, 0);
    }

#pragma unroll
    for (int p = 0; p < 4; ++p) {
        const int pix = p * 16 + col;
        if (pix >= Wdim) continue;
#pragma unroll
        for (int m = 0; m < 3; ++m) {
            const int o0 = wave * 48 + m * 16 + kb * 4;
            float* yp = y + ((size_t)(n * C_OUT + o0)) * HWsz + h * Wdim + pix;
#pragma unroll
            for (int r = 0; r < 4; ++r) yp[(size_t)r * HWsz] = acc[m][p][r];
        }
    }
}

extern "C" void kernel_launch(void* const* d_in, const int* in_sizes, int n_in,
                              void* d_out, int out_size, void* d_ws, size_t ws_size,
                              hipStream_t stream) {
    const float* x   = (const float*)d_in[0];
    const float* wdw = (const float*)d_in[1];
    const float* wpw = (const float*)d_in[2];
    float* y = (float*)d_out;

    short* apre = (short*)d_ws;                       // 294912 B
    const size_t DW_OFF   = 512 * 1024;
    const size_t DW_BYTES = (size_t)32 * HWsz * C_IN * 2;   // 77,070,336 B

    if (ws_size >= DW_OFF + DW_BYTES) {
        short* dwws = (short*)((char*)d_ws + DW_OFF);
        hipLaunchKernelGGL(dw_kernel, dim3(NBLKDW + NPREP), dim3(256),
                           0, stream, x, wdw, wpw, apre, dwws);
        hipLaunchKernelGGL(pw_kernel, dim3(HWsz / 64, 32), dim3(256),
                           0, stream, apre, dwws, y);
    } else {
        hipLaunchKernelGGL(prep_w_kernel, dim3((C_OUT * C_IN + 255) / 256), dim3(256),
                           0, stream, wpw, apre);
        hipLaunchKernelGGL(fused_dwpw_kernel, dim3(Hdim, 32), dim3(512),
                           0, stream, x, wdw, apre, y);
    }
}

// Round 14
// 100.588 us; speedup vs baseline: 1.1730x; 1.1730x over previous
//
#include <hip/hip_runtime.h>
#include <hip/hip_bf16.h>
#include <stdint.h>

typedef float  f32x4  __attribute__((ext_vector_type(4)));
typedef short  bf16x8 __attribute__((ext_vector_type(8)));
typedef short  bf16x4 __attribute__((ext_vector_type(4)));

#define C_IN   384
#define C_OUT  384
#define Hdim   56
#define Wdim   56
#define HWsz   3136
#define KC     32
#define NCHUNK 12
#define NOSUB  24
#define SLAB   ((size_t)HWsz * 8)    // shorts per (n,cblk,g) slab
#define BSTR   ((size_t)HWsz * KC)   // shorts per (n,cblk) = 4 slabs
#define RB     8                     // output rows per wave (dw); halo 10/8 = 1.25x
#define NRB    (Hdim / RB)           // 7
#define NBLKDW (NRB * NCHUNK * 32)   // 2688, %8==0
#define NPREP  ((C_OUT * C_IN) / 256) // 576 prep blocks folded into dw grid

__device__ __forceinline__ short f2bf(float f) {
    union { float f; uint32_t u; } v; v.f = f;
    uint32_t u = v.u + (0x7FFFu + ((v.u >> 16) & 1u));   // RNE
    return (short)(u >> 16);
}

__device__ __forceinline__ uint32_t cvtpk_bf16(float lo, float hi) {
    uint32_t r;
    asm("v_cvt_pk_bf16_f32 %0, %1, %2" : "=v"(r) : "v"(lo), "v"(hi));
    return r;   // lo in bits[15:0], hi in bits[31:16]
}

__device__ __forceinline__ void stage16(const short* g, const short* l) {
    __builtin_amdgcn_global_load_lds(
        (const __attribute__((address_space(1))) void*)g,
        (__attribute__((address_space(3))) void*)l, 16, 0, 0);
}

template<int N> __device__ __forceinline__ void wait_vmcnt() {
    if constexpr (N == 0)      asm volatile("s_waitcnt vmcnt(0)" ::: "memory");
    else if constexpr (N == 1) asm volatile("s_waitcnt vmcnt(1)" ::: "memory");
    else                       asm volatile("s_waitcnt vmcnt(2)" ::: "memory");
}
__device__ __forceinline__ void block_barrier() {
    asm volatile("" ::: "memory");
    __builtin_amdgcn_s_barrier();
    asm volatile("" ::: "memory");
}

// ---------------- W prepack ----------------
// flat idx = ((cblk*24 + osub)*64 + lane)*8 + j
// value    = bf16( w_pw[ (osub*16 + (lane&15)) * 384 + cblk*32 + (lane>>4)*8 + j ] )
__device__ __forceinline__ void prep_w_one(const float* __restrict__ wpw,
                                           short* __restrict__ apre, int idx) {
    int j    = idx & 7;
    int lane = (idx >> 3) & 63;
    int osub = (idx >> 9) % NOSUB;
    int cblk = idx / (NOSUB * 512);
    int o = osub * 16 + (lane & 15);
    int c = cblk * KC + (lane >> 4) * 8 + j;
    apre[idx] = f2bf(wpw[o * C_IN + c]);
}

__global__ void prep_w_kernel(const float* __restrict__ wpw, short* __restrict__ apre) {
    int idx = blockIdx.x * 256 + threadIdx.x;
    if (idx < C_OUT * C_IN) prep_w_one(wpw, apre, idx);
}

// ---------------- Depthwise v11 + folded W-prepack ----------------
// Wave = 8 ch x 8 output rows (10 input rows, halo 1.25x). No fence, no VGPR cap:
// compiler schedules loads freely (R12 proved fence-neutral; R13 proved caps+fence
// spill). Vertical-first conv + packed shuffles. Stores slab-contiguous 16B/lane.
__global__ __launch_bounds__(256) void dw_kernel(
    const float* __restrict__ x, const float* __restrict__ wdw,
    const float* __restrict__ wpw, short* __restrict__ apre,
    short* __restrict__ dwws) {

    const int p = (int)blockIdx.x;
    if (p >= NBLKDW) {   // folded prepack
        const int idx = (p - NBLKDW) * 256 + (int)threadIdx.x;
        if (idx < C_OUT * C_IN) prep_w_one(wpw, apre, idx);
        return;
    }

    const int l  = (p & 7) * (NBLKDW / 8) + (p >> 3);
    const int rb   = l % NRB;
    const int cblk = (l / NRB) % NCHUNK;
    const int n    = l / (NRB * NCHUNK);

    const int wave = (int)threadIdx.x >> 6;
    const int lane = (int)threadIdx.x & 63;
    const int c0u  = __builtin_amdgcn_readfirstlane(cblk * KC + wave * 8);
    const int h0   = rb * RB;

    const float* xb = x + ((size_t)n * C_IN + c0u) * HWsz;

    float v[8][RB + 2];
#pragma unroll
    for (int q = 0; q < 8; ++q)
#pragma unroll
        for (int d = 0; d < RB + 2; ++d) {
            const int hh = h0 + d - 1;
            const bool ok = (hh >= 0) && (hh < Hdim) && (lane < Wdim);
            v[q][d] = ok ? xb[(size_t)q * HWsz + hh * Wdim + lane] : 0.f;
        }

    const float* wp = wdw + c0u * 9;
    float wk[8][9];
#pragma unroll
    for (int q = 0; q < 8; ++q)
#pragma unroll
        for (int t = 0; t < 9; ++t) wk[q][t] = wp[q * 9 + t];

    bf16x8 pk[RB];
#pragma unroll
    for (int qq = 0; qq < 8; qq += 2) {
#pragma unroll
        for (int r = 0; r < RB; ++r) {
            // vertical conv per channel pair: t_d = sum_dr w[dr*3+d]*v[r+dr]
            float tA[3], tB[3];
#pragma unroll
            for (int d = 0; d < 3; ++d) {
                tA[d] = wk[qq][d] * v[qq][r];
                tA[d] = fmaf(wk[qq][3 + d], v[qq][r + 1], tA[d]);
                tA[d] = fmaf(wk[qq][6 + d], v[qq][r + 2], tA[d]);
                tB[d] = wk[qq + 1][d] * v[qq + 1][r];
                tB[d] = fmaf(wk[qq + 1][3 + d], v[qq + 1][r + 1], tB[d]);
                tB[d] = fmaf(wk[qq + 1][6 + d], v[qq + 1][r + 2], tB[d]);
            }
            // horizontal combine: out(p) = t0(p-1) + t1(p) + t2(p+1)
            uint32_t p0 = cvtpk_bf16(tA[0], tB[0]);
            uint32_t p2 = cvtpk_bf16(tA[2], tB[2]);
            uint32_t l0 = __shfl_up(p0, 1);
            if (lane == 0) l0 = 0u;                  // left zero-pad
            uint32_t r2 = __shfl_down(p2, 1);        // lane55 pulls lane56 (zeros)
            const float lfA = __uint_as_float(l0 << 16);
            const float lfB = __uint_as_float(l0 & 0xFFFF0000u);
            const float rtA = __uint_as_float(r2 << 16);
            const float rtB = __uint_as_float(r2 & 0xFFFF0000u);
            pk[r][qq]     = f2bf(tA[1] + lfA + rtA);
            pk[r][qq + 1] = f2bf(tB[1] + lfB + rtB);
        }
    }

    if (lane < Wdim) {
        short* sb = dwws + (((size_t)n * NCHUNK + cblk) * 4 + wave) * SLAB;
#pragma unroll
        for (int r = 0; r < RB; ++r)
            *reinterpret_cast<bf16x8*>(sb + ((size_t)(h0 + r) * Wdim + lane) * 8)
                = pk[r];
    }
}

// ---------------- Pointwise GEMM v7: LDS-staged B, depth-3 pipeline, nt y-stores -----
// grid (49 pb, 32 n), 256 threads (4 waves). Wave owns 96 o x 64 pix.
// B layout [n][cblk][g][pix][c8], slab g = kb. Stage: thread t -> LDS unit t
// (linear); global source pixel XOR-swizzled (involution) for bank spread.
__global__ __launch_bounds__(256, 3) void pw_kernel(
    const short* __restrict__ apre, const short* __restrict__ dwws,
    float* __restrict__ y) {

    __shared__ __align__(16) short Bt[4][64 * KC];   // 4 x 4 KB

    const int pb   = blockIdx.x;
    const int n    = blockIdx.y;
    const int wave = (int)threadIdx.x >> 6;
    const int lane = (int)threadIdx.x & 63;
    const int col  = lane & 15;
    const int kb   = lane >> 4;

    f32x4 acc[6][4];
#pragma unroll
    for (int m = 0; m < 6; ++m)
#pragma unroll
        for (int q = 0; q < 4; ++q) acc[m][q] = (f32x4)0.f;

    // stage mapping: g = wave, physical pixel unit = lane
    const int plog = (lane & ~7) | ((lane ^ (lane >> 3) ^ (wave << 1)) & 7);
    const short* gsrc0 = dwws + (size_t)n * NCHUNK * BSTR + (size_t)wave * SLAB
                       + ((size_t)pb * 64 + plog) * 8;
    const short* lbase = &Bt[0][0] + (wave << 9);   // wave's 1KB quarter of buffer 0

    // read offsets: logical (kb, pix) lives at unit kb*64 + swz(kb, pix)
    int rd[4];
#pragma unroll
    for (int q = 0; q < 4; ++q) {
        const int pix = q * 16 + col;
        const int ppx = (pix & ~7) | ((pix ^ (pix >> 3) ^ (kb << 1)) & 7);
        rd[q] = (kb * 64 + ppx) * 8;
    }

#define STAGE(b, ch) stage16(gsrc0 + (size_t)(ch) * BSTR, lbase + (b) * (64 * KC))

    STAGE(0, 0);
    STAGE(1, 1);
    STAGE(2, 2);

#pragma unroll
    for (int ch = 0; ch < NCHUNK; ++ch) {
        if (ch <= NCHUNK - 3)      wait_vmcnt<2>();
        else if (ch == NCHUNK - 2) wait_vmcnt<1>();
        else                       wait_vmcnt<0>();
        block_barrier();

        // A-fragments first (their implicit wait never drains the stage below)
        bf16x8 af[6];
#pragma unroll
        for (int m = 0; m < 6; ++m)
            af[m] = *reinterpret_cast<const bf16x8*>(
                apre + (((ch * NOSUB + wave * 6 + m) * 64 + lane) << 3));

        if (ch + 3 < NCHUNK) STAGE((ch + 3) & 3, ch + 3);

        bf16x8 bfr[4];
#pragma unroll
        for (int q = 0; q < 4; ++q)
            bfr[q] = *reinterpret_cast<const bf16x8*>(&Bt[ch & 3][rd[q]]);

#pragma unroll
        for (int m = 0; m < 6; ++m)
#pragma unroll
            for (int q = 0; q < 4; ++q)
                acc[m][q] = __builtin_amdgcn_mfma_f32_16x16x32_bf16(
                    af[m], bfr[q], acc[m][q], 0, 0, 0);
    }
#undef STAGE

    // ---- epilogue: o = wave*96 + m*16 + kb*4 + r ; pix = q*16 + col ; nt stores ----
#pragma unroll
    for (int m = 0; m < 6; ++m) {
        const int o = wave * 96 + m * 16 + kb * 4;
        float* yo = y + ((size_t)(n * C_OUT + o)) * HWsz + pb * 64;
#pragma unroll
        for (int q = 0; q < 4; ++q) {
            const int pix = q * 16 + col;
#pragma unroll
            for (int r = 0; r < 4; ++r)
                __builtin_nontemporal_store(acc[m][q][r], yo + (size_t)r * HWsz + pix);
        }
    }
}

// ---------------- Fallback fused kernel (round-1, correct but slow) ----------------
#define LDSS 40
__global__ __launch_bounds__(512) void fused_dwpw_kernel(
    const float* __restrict__ x, const float* __restrict__ wdw,
    const short* __restrict__ apre, float* __restrict__ y) {

    __shared__ __align__(16) short dw_lds[64 * LDSS];

    const int h    = blockIdx.x;
    const int n    = blockIdx.y;
    const int tid  = (int)threadIdx.x;
    const int wave = tid >> 6;
    const int lane = tid & 63;
    const int col  = lane & 15;
    const int kb   = lane >> 4;

    f32x4 acc[3][4];
#pragma unroll
    for (int m = 0; m < 3; ++m)
#pragma unroll
        for (int p = 0; p < 4; ++p) acc[m][p] = (f32x4)0.f;

    const float* xn = x + (size_t)n * C_IN * HWsz;

    for (int ch = 0; ch < NCHUNK; ++ch) {
        short dwv[4];
#pragma unroll
        for (int q = 0; q < 4; ++q) {
            const int c = ch * KC + wave * 4 + q;
            const float* xc = xn + (size_t)c * HWsz;
            const float* wkp = wdw + c * 9;
            float a0 = 0.f;
#pragma unroll
            for (int r = 0; r < 3; ++r) {
                const int hh = h + r - 1;
                float xv = 0.f;
                if (hh >= 0 && hh < Hdim && lane < Wdim) xv = xc[hh * Wdim + lane];
                float lf = __shfl_up(xv, 1);
                if (lane == 0) lf = 0.f;
                float rt = __shfl_down(xv, 1);
                a0 = fmaf(wkp[r * 3 + 0], lf, a0);
                a0 = fmaf(wkp[r * 3 + 1], xv, a0);
                a0 = fmaf(wkp[r * 3 + 2], rt, a0);
            }
            if (lane >= Wdim) a0 = 0.f;
            dwv[q] = f2bf(a0);
        }

        __syncthreads();
        {
            bf16x4 pk2; pk2[0] = dwv[0]; pk2[1] = dwv[1]; pk2[2] = dwv[2]; pk2[3] = dwv[3];
            *reinterpret_cast<bf16x4*>(&dw_lds[lane * LDSS + wave * 4]) = pk2;
        }
        __syncthreads();

        bf16x8 afr[3], bfr[4];
#pragma unroll
        for (int m = 0; m < 3; ++m)
            afr[m] = *reinterpret_cast<const bf16x8*>(
                apre + (((ch * NOSUB + wave * 3 + m) * 64 + lane) << 3));
#pragma unroll
        for (int p = 0; p < 4; ++p)
            bfr[p] = *reinterpret_cast<const bf16x8*>(
                &dw_lds[(p * 16 + col) * LDSS + kb * 8]);
#pragma unroll
        for (int m = 0; m < 3; ++m)
#pragma unroll
            for (int p = 0; p < 4; ++p)
                acc[m][p] = __builtin_amdgcn_mfma_f32_16x16x32_bf16(
                    afr[m], bfr[p], acc[m][p], 0, 0, 0);
    }

#pragma unroll
    for (int p = 0; p < 4; ++p) {
        const int pix = p * 16 + col;
        if (pix >= Wdim) continue;
#pragma unroll
        for (int m = 0; m < 3; ++m) {
            const int o0 = wave * 48 + m * 16 + kb * 4;
            float* yp = y + ((size_t)(n * C_OUT + o0)) * HWsz + h * Wdim + pix;
#pragma unroll
            for (int r = 0; r < 4; ++r) yp[(size_t)r * HWsz] = acc[m][p][r];
        }
    }
}

extern "C" void kernel_launch(void* const* d_in, const int* in_sizes, int n_in,
                              void* d_out, int out_size, void* d_ws, size_t ws_size,
                              hipStream_t stream) {
    const float* x   = (const float*)d_in[0];
    const float* wdw = (const float*)d_in[1];
    const float* wpw = (const float*)d_in[2];
    float* y = (float*)d_out;

    short* apre = (short*)d_ws;                       // 294912 B
    const size_t DW_OFF   = 512 * 1024;
    const size_t DW_BYTES = (size_t)32 * HWsz * C_IN * 2;   // 77,070,336 B

    if (ws_size >= DW_OFF + DW_BYTES) {
        short* dwws = (short*)((char*)d_ws + DW_OFF);
        hipLaunchKernelGGL(dw_kernel, dim3(NBLKDW + NPREP), dim3(256),
                           0, stream, x, wdw, wpw, apre, dwws);
        hipLaunchKernelGGL(pw_kernel, dim3(HWsz / 64, 32), dim3(256),
                           0, stream, apre, dwws, y);
    } else {
        hipLaunchKernelGGL(prep_w_kernel, dim3((C_OUT * C_IN + 255) / 256), dim3(256),
                           0, stream, wpw, apre);
        hipLaunchKernelGGL(fused_dwpw_kernel, dim3(Hdim, 32), dim3(512),
                           0, stream, x, wdw, apre, y);
    }
}

// Round 15
// 96.307 us; speedup vs baseline: 1.2252x; 1.0444x over previous
//
#include <hip/hip_runtime.h>
#include <hip/hip_bf16.h>
#include <stdint.h>

typedef float  f32x4  __attribute__((ext_vector_type(4)));
typedef short  bf16x8 __attribute__((ext_vector_type(8)));
typedef short  bf16x4 __attribute__((ext_vector_type(4)));

#define C_IN   384
#define C_OUT  384
#define Hdim   56
#define Wdim   56
#define HWsz   3136
#define KC     32
#define NCHUNK 12
#define NOSUB  24
#define SLAB   ((size_t)HWsz * 8)    // shorts per (n,cblk,g) slab
#define BSTR   ((size_t)HWsz * KC)   // shorts per (n,cblk) = 4 slabs
#define RB     4                     // output rows per wave (dw) — best of {4,7,8}
#define NRB    (Hdim / RB)           // 14
#define NBLKDW (NRB * NCHUNK * 32)   // 5376, %8==0
#define NPREP  ((C_OUT * C_IN) / 256) // 576 prep blocks folded into dw grid

__device__ __forceinline__ short f2bf(float f) {
    union { float f; uint32_t u; } v; v.f = f;
    uint32_t u = v.u + (0x7FFFu + ((v.u >> 16) & 1u));   // RNE
    return (short)(u >> 16);
}

__device__ __forceinline__ uint32_t cvtpk_bf16(float lo, float hi) {
    uint32_t r;
    asm("v_cvt_pk_bf16_f32 %0, %1, %2" : "=v"(r) : "v"(lo), "v"(hi));
    return r;   // lo in bits[15:0], hi in bits[31:16]
}

__device__ __forceinline__ void stage16(const short* g, const short* l) {
    __builtin_amdgcn_global_load_lds(
        (const __attribute__((address_space(1))) void*)g,
        (__attribute__((address_space(3))) void*)l, 16, 0, 0);
}

template<int N> __device__ __forceinline__ void wait_vmcnt() {
    if constexpr (N == 0)      asm volatile("s_waitcnt vmcnt(0)" ::: "memory");
    else if constexpr (N == 1) asm volatile("s_waitcnt vmcnt(1)" ::: "memory");
    else                       asm volatile("s_waitcnt vmcnt(2)" ::: "memory");
}
__device__ __forceinline__ void block_barrier() {
    asm volatile("" ::: "memory");
    __builtin_amdgcn_s_barrier();
    asm volatile("" ::: "memory");
}

// ---------------- W prepack ----------------
// flat idx = ((cblk*24 + osub)*64 + lane)*8 + j
// value    = bf16( w_pw[ (osub*16 + (lane&15)) * 384 + cblk*32 + (lane>>4)*8 + j ] )
__device__ __forceinline__ void prep_w_one(const float* __restrict__ wpw,
                                           short* __restrict__ apre, int idx) {
    int j    = idx & 7;
    int lane = (idx >> 3) & 63;
    int osub = (idx >> 9) % NOSUB;
    int cblk = idx / (NOSUB * 512);
    int o = osub * 16 + (lane & 15);
    int c = cblk * KC + (lane >> 4) * 8 + j;
    apre[idx] = f2bf(wpw[o * C_IN + c]);
}

__global__ void prep_w_kernel(const float* __restrict__ wpw, short* __restrict__ apre) {
    int idx = blockIdx.x * 256 + threadIdx.x;
    if (idx < C_OUT * C_IN) prep_w_one(wpw, apre, idx);
}

// ---------------- Depthwise v8 + folded W-prepack (R11 config — measured best) -------
// Wave = 8 ch x 4 output rows. Vertical-first conv (t0/t1/t2 per out row);
// 2 channels share one shuffle via v_cvt_pk_bf16_f32 (32 DS ops/wave).
// Stores: slab-per-wave layout [n][cblk][g][pix][c8] -> 16B/lane fully contiguous
// (write amplification structurally impossible). No fence (R12: neutral),
// no VGPR cap (R13: cap+fence spills), RB=4 (R13/R14: 7 and 8 both slower).
__global__ __launch_bounds__(256) void dw_kernel(
    const float* __restrict__ x, const float* __restrict__ wdw,
    const float* __restrict__ wpw, short* __restrict__ apre,
    short* __restrict__ dwws) {

    const int p = (int)blockIdx.x;
    if (p >= NBLKDW) {   // folded prepack
        const int idx = (p - NBLKDW) * 256 + (int)threadIdx.x;
        if (idx < C_OUT * C_IN) prep_w_one(wpw, apre, idx);
        return;
    }

    const int l  = (p & 7) * (NBLKDW / 8) + (p >> 3);   // XCD-chunked bijective swizzle
    const int rb   = l % NRB;
    const int cblk = (l / NRB) % NCHUNK;
    const int n    = l / (NRB * NCHUNK);

    const int wave = (int)threadIdx.x >> 6;
    const int lane = (int)threadIdx.x & 63;
    const int c0u  = __builtin_amdgcn_readfirstlane(cblk * KC + wave * 8);
    const int h0   = rb * RB;

    const float* xb = x + ((size_t)n * C_IN + c0u) * HWsz;

    float v[8][RB + 2];
#pragma unroll
    for (int q = 0; q < 8; ++q)
#pragma unroll
        for (int d = 0; d < RB + 2; ++d) {
            const int hh = h0 + d - 1;
            const bool ok = (hh >= 0) && (hh < Hdim) && (lane < Wdim);
            v[q][d] = ok ? xb[(size_t)q * HWsz + hh * Wdim + lane] : 0.f;
        }

    const float* wp = wdw + c0u * 9;
    float wk[8][9];
#pragma unroll
    for (int q = 0; q < 8; ++q)
#pragma unroll
        for (int t = 0; t < 9; ++t) wk[q][t] = wp[q * 9 + t];

    bf16x8 pk[RB];
#pragma unroll
    for (int qq = 0; qq < 8; qq += 2) {
#pragma unroll
        for (int r = 0; r < RB; ++r) {
            // vertical conv per channel pair: t_d = sum_dr w[dr*3+d]*v[r+dr]
            float tA[3], tB[3];
#pragma unroll
            for (int d = 0; d < 3; ++d) {
                tA[d] = wk[qq][d] * v[qq][r];
                tA[d] = fmaf(wk[qq][3 + d], v[qq][r + 1], tA[d]);
                tA[d] = fmaf(wk[qq][6 + d], v[qq][r + 2], tA[d]);
                tB[d] = wk[qq + 1][d] * v[qq + 1][r];
                tB[d] = fmaf(wk[qq + 1][3 + d], v[qq + 1][r + 1], tB[d]);
                tB[d] = fmaf(wk[qq + 1][6 + d], v[qq + 1][r + 2], tB[d]);
            }
            // horizontal combine: out(p) = t0(p-1) + t1(p) + t2(p+1)
            uint32_t p0 = cvtpk_bf16(tA[0], tB[0]);
            uint32_t p2 = cvtpk_bf16(tA[2], tB[2]);
            uint32_t l0 = __shfl_up(p0, 1);
            if (lane == 0) l0 = 0u;                  // left zero-pad
            uint32_t r2 = __shfl_down(p2, 1);        // lane55 pulls lane56 (zeros)
            const float lfA = __uint_as_float(l0 << 16);
            const float lfB = __uint_as_float(l0 & 0xFFFF0000u);
            const float rtA = __uint_as_float(r2 << 16);
            const float rtB = __uint_as_float(r2 & 0xFFFF0000u);
            pk[r][qq]     = f2bf(tA[1] + lfA + rtA);
            pk[r][qq + 1] = f2bf(tB[1] + lfB + rtB);
        }
    }

    if (lane < Wdim) {
        short* sb = dwws + (((size_t)n * NCHUNK + cblk) * 4 + wave) * SLAB;
#pragma unroll
        for (int r = 0; r < RB; ++r)
            *reinterpret_cast<bf16x8*>(sb + ((size_t)(h0 + r) * Wdim + lane) * 8)
                = pk[r];
    }
}

// ---------------- Pointwise GEMM v7: LDS-staged B, depth-3 pipeline, nt y-stores -----
// grid (49 pb, 32 n), 256 threads (4 waves). Wave owns 96 o x 64 pix.
// B layout [n][cblk][g][pix][c8], slab g = wave. Stage: thread t -> LDS unit t
// (linear dest, rule #21); global source pixel XOR-swizzled (involution) for bank
// spread on the ds_read_b128 fragment reads. ONE raw barrier per chunk; counted
// vmcnt keeps 2 stages in flight across barriers. y stores non-temporal so the
// 154 MB output never evicts the L3-resident x/dwws working set.
__global__ __launch_bounds__(256, 3) void pw_kernel(
    const short* __restrict__ apre, const short* __restrict__ dwws,
    float* __restrict__ y) {

    __shared__ __align__(16) short Bt[4][64 * KC];   // 4 x 4 KB

    const int pb   = blockIdx.x;
    const int n    = blockIdx.y;
    const int wave = (int)threadIdx.x >> 6;
    const int lane = (int)threadIdx.x & 63;
    const int col  = lane & 15;
    const int kb   = lane >> 4;

    f32x4 acc[6][4];
#pragma unroll
    for (int m = 0; m < 6; ++m)
#pragma unroll
        for (int q = 0; q < 4; ++q) acc[m][q] = (f32x4)0.f;

    // stage mapping: g = wave, physical pixel unit = lane
    const int plog = (lane & ~7) | ((lane ^ (lane >> 3) ^ (wave << 1)) & 7);
    const short* gsrc0 = dwws + (size_t)n * NCHUNK * BSTR + (size_t)wave * SLAB
                       + ((size_t)pb * 64 + plog) * 8;
    const short* lbase = &Bt[0][0] + (wave << 9);   // wave's 1KB quarter of buffer 0

    // read offsets: logical (kb, pix) lives at unit kb*64 + swz(kb, pix)
    int rd[4];
#pragma unroll
    for (int q = 0; q < 4; ++q) {
        const int pix = q * 16 + col;
        const int ppx = (pix & ~7) | ((pix ^ (pix >> 3) ^ (kb << 1)) & 7);
        rd[q] = (kb * 64 + ppx) * 8;
    }

#define STAGE(b, ch) stage16(gsrc0 + (size_t)(ch) * BSTR, lbase + (b) * (64 * KC))

    STAGE(0, 0);
    STAGE(1, 1);
    STAGE(2, 2);

#pragma unroll
    for (int ch = 0; ch < NCHUNK; ++ch) {
        if (ch <= NCHUNK - 3)      wait_vmcnt<2>();
        else if (ch == NCHUNK - 2) wait_vmcnt<1>();
        else                       wait_vmcnt<0>();
        block_barrier();

        // A-fragments first (their implicit wait never drains the stage below)
        bf16x8 af[6];
#pragma unroll
        for (int m = 0; m < 6; ++m)
            af[m] = *reinterpret_cast<const bf16x8*>(
                apre + (((ch * NOSUB + wave * 6 + m) * 64 + lane) << 3));

        if (ch + 3 < NCHUNK) STAGE((ch + 3) & 3, ch + 3);

        bf16x8 bfr[4];
#pragma unroll
        for (int q = 0; q < 4; ++q)
            bfr[q] = *reinterpret_cast<const bf16x8*>(&Bt[ch & 3][rd[q]]);

#pragma unroll
        for (int m = 0; m < 6; ++m)
#pragma unroll
            for (int q = 0; q < 4; ++q)
                acc[m][q] = __builtin_amdgcn_mfma_f32_16x16x32_bf16(
                    af[m], bfr[q], acc[m][q], 0, 0, 0);
    }
#undef STAGE

    // ---- epilogue: o = wave*96 + m*16 + kb*4 + r ; pix = q*16 + col ; nt stores ----
#pragma unroll
    for (int m = 0; m < 6; ++m) {
        const int o = wave * 96 + m * 16 + kb * 4;
        float* yo = y + ((size_t)(n * C_OUT + o)) * HWsz + pb * 64;
#pragma unroll
        for (int q = 0; q < 4; ++q) {
            const int pix = q * 16 + col;
#pragma unroll
            for (int r = 0; r < 4; ++r)
                __builtin_nontemporal_store(acc[m][q][r], yo + (size_t)r * HWsz + pix);
        }
    }
}

// ---------------- Fallback fused kernel (round-1, correct but slow) ----------------
#define LDSS 40
__global__ __launch_bounds__(512) void fused_dwpw_kernel(
    const float* __restrict__ x, const float* __restrict__ wdw,
    const short* __restrict__ apre, float* __restrict__ y) {

    __shared__ __align__(16) short dw_lds[64 * LDSS];

    const int h    = blockIdx.x;
    const int n    = blockIdx.y;
    const int tid  = (int)threadIdx.x;
    const int wave = tid >> 6;
    const int lane = tid & 63;
    const int col  = lane & 15;
    const int kb   = lane >> 4;

    f32x4 acc[3][4];
#pragma unroll
    for (int m = 0; m < 3; ++m)
#pragma unroll
        for (int p = 0; p < 4; ++p) acc[m][p] = (f32x4)0.f;

    const float* xn = x + (size_t)n * C_IN * HWsz;

    for (int ch = 0; ch < NCHUNK; ++ch) {
        short dwv[4];
#pragma unroll
        for (int q = 0; q < 4; ++q) {
            const int c = ch * KC + wave * 4 + q;
            const float* xc = xn + (size_t)c * HWsz;
            const float* wkp = wdw + c * 9;
            float a0 = 0.f;
#pragma unroll
            for (int r = 0; r < 3; ++r) {
                const int hh = h + r - 1;
                float xv = 0.f;
                if (hh >= 0 && hh < Hdim && lane < Wdim) xv = xc[hh * Wdim + lane];
                float lf = __shfl_up(xv, 1);
                if (lane == 0) lf = 0.f;
                float rt = __shfl_down(xv, 1);
                a0 = fmaf(wkp[r * 3 + 0], lf, a0);
                a0 = fmaf(wkp[r * 3 + 1], xv, a0);
                a0 = fmaf(wkp[r * 3 + 2], rt, a0);
            }
            if (lane >= Wdim) a0 = 0.f;
            dwv[q] = f2bf(a0);
        }

        __syncthreads();
        {
            bf16x4 pk2; pk2[0] = dwv[0]; pk2[1] = dwv[1]; pk2[2] = dwv[2]; pk2[3] = dwv[3];
            *reinterpret_cast<bf16x4*>(&dw_lds[lane * LDSS + wave * 4]) = pk2;
        }
        __syncthreads();

        bf16x8 afr[3], bfr[4];
#pragma unroll
        for (int m = 0; m < 3; ++m)
            afr[m] = *reinterpret_cast<const bf16x8*>(
                apre + (((ch * NOSUB + wave * 3 + m) * 64 + lane) << 3));
#pragma unroll
        for (int p = 0; p < 4; ++p)
            bfr[p] = *reinterpret_cast<const bf16x8*>(
                &dw_lds[(p * 16 + col) * LDSS + kb * 8]);
#pragma unroll
        for (int m = 0; m < 3; ++m)
#pragma unroll
            for (int p = 0; p < 4; ++p)
                acc[m][p] = __builtin_amdgcn_mfma_f32_16x16x32_bf16(
                    afr[m], bfr[p], acc[m][p], 0, 0, 0);
    }

#pragma unroll
    for (int p = 0; p < 4; ++p) {
        const int pix = p * 16 + col;
        if (pix >= Wdim) continue;
#pragma unroll
        for (int m = 0; m < 3; ++m) {
            const int o0 = wave * 48 + m * 16 + kb * 4;
            float* yp = y + ((size_t)(n * C_OUT + o0)) * HWsz + h * Wdim + pix;
#pragma unroll
            for (int r = 0; r < 4; ++r) yp[(size_t)r * HWsz] = acc[m][p][r];
        }
    }
}

extern "C" void kernel_launch(void* const* d_in, const int* in_sizes, int n_in,
                              void* d_out, int out_size, void* d_ws, size_t ws_size,
                              hipStream_t stream) {
    const float* x   = (const float*)d_in[0];
    const float* wdw = (const float*)d_in[1];
    const float* wpw = (const float*)d_in[2];
    float* y = (float*)d_out;

    short* apre = (short*)d_ws;                       // 294912 B
    const size_t DW_OFF   = 512 * 1024;
    const size_t DW_BYTES = (size_t)32 * HWsz * C_IN * 2;   // 77,070,336 B

    if (ws_size >= DW_OFF + DW_BYTES) {
        short* dwws = (short*)((char*)d_ws + DW_OFF);
        hipLaunchKernelGGL(dw_kernel, dim3(NBLKDW + NPREP), dim3(256),
                           0, stream, x, wdw, wpw, apre, dwws);
        hipLaunchKernelGGL(pw_kernel, dim3(HWsz / 64, 32), dim3(256),
                           0, stream, apre, dwws, y);
    } else {
        hipLaunchKernelGGL(prep_w_kernel, dim3((C_OUT * C_IN + 255) / 256), dim3(256),
                           0, stream, wpw, apre);
        hipLaunchKernelGGL(fused_dwpw_kernel, dim3(Hdim, 32), dim3(512),
                           0, stream, x, wdw, apre, y);
    }
}